// Round 6
// baseline (1131.912 us; speedup 1.0000x reference)
//
#include <hip/hip_runtime.h>

#define N_NODES 200000
#define N_EDGES 600000
#define N_GRAPHS 10000
#define F_NODE 32
#define HDIM 128
#define BN_EPS 1e-5f

typedef unsigned short ushort_t;
typedef unsigned int uint_t;
typedef __attribute__((ext_vector_type(8))) short short8;
typedef __attribute__((ext_vector_type(4))) float f32x4;

__device__ __forceinline__ ushort_t f2bf(float f) {
    uint_t u = __builtin_bit_cast(uint_t, f);
    u += 0x7FFFu + ((u >> 16) & 1u);   // RNE
    return (ushort_t)(u >> 16);
}
__device__ __forceinline__ float bf2f(ushort_t h) {
    uint_t u = ((uint_t)h) << 16;
    return __builtin_bit_cast(float, u);
}

// ---------------- zero fill ----------------
__global__ __launch_bounds__(256) void fill_zero_k(uint_t* __restrict__ p, long long n)
{
    long long gid = (long long)blockIdx.x * blockDim.x + threadIdx.x;
    long long stride = (long long)gridDim.x * blockDim.x;
    for (long long i = gid; i < n; i += stride) p[i] = 0u;
}

// ---------------- f32 -> bf16 convert (x) ----------------
__global__ __launch_bounds__(256) void cvt_bf16_k(
    const float* __restrict__ in, ushort_t* __restrict__ outp, long long n8)
{
    long long gid = (long long)blockIdx.x * blockDim.x + threadIdx.x;
    if (gid >= n8) return;
    const float4* ip = (const float4*)(in + gid * 8);
    float4 a = ip[0], b = ip[1];
    uint4 u;
    u.x = (uint_t)f2bf(a.x) | ((uint_t)f2bf(a.y) << 16);
    u.y = (uint_t)f2bf(a.z) | ((uint_t)f2bf(a.w) << 16);
    u.z = (uint_t)f2bf(b.x) | ((uint_t)f2bf(b.y) << 16);
    u.w = (uint_t)f2bf(b.z) | ((uint_t)f2bf(b.w) << 16);
    *reinterpret_cast<uint4*>(outp + gid * 8) = u;
}

// ---------------- CSR build ----------------
__global__ __launch_bounds__(256) void hist_k(const int* __restrict__ dst, int* __restrict__ deg)
{
    int e = blockIdx.x * 256 + threadIdx.x;
    if (e < N_EDGES) atomicAdd(&deg[dst[e]], 1);
}

__global__ __launch_bounds__(256) void scan_blocks_k(
    const int* __restrict__ deg, int* __restrict__ incl, int* __restrict__ bsum)
{
    __shared__ int sh[256];
    int i = blockIdx.x * 256 + threadIdx.x;
    int v = (i < N_NODES) ? deg[i] : 0;
    sh[threadIdx.x] = v;
    __syncthreads();
    #pragma unroll
    for (int off = 1; off < 256; off <<= 1) {
        int t = (threadIdx.x >= off) ? sh[threadIdx.x - off] : 0;
        __syncthreads();
        sh[threadIdx.x] += t;
        __syncthreads();
    }
    if (i < N_NODES) incl[i] = sh[threadIdx.x];
    if (threadIdx.x == 255) bsum[blockIdx.x] = sh[255];
}

__global__ __launch_bounds__(256) void scan_bsum_k(int* __restrict__ bsum, int nb)
{
    __shared__ int sh[256];
    int run = 0;
    for (int base = 0; base < nb; base += 256) {
        int i = base + threadIdx.x;
        int v = (i < nb) ? bsum[i] : 0;
        sh[threadIdx.x] = v;
        __syncthreads();
        #pragma unroll
        for (int off = 1; off < 256; off <<= 1) {
            int t = (threadIdx.x >= off) ? sh[threadIdx.x - off] : 0;
            __syncthreads();
            sh[threadIdx.x] += t;
            __syncthreads();
        }
        if (i < nb) bsum[i] = run + sh[threadIdx.x] - v;  // exclusive
        run += sh[255];
        __syncthreads();
    }
}

__global__ __launch_bounds__(256) void finalize_csr_k(
    const int* __restrict__ deg, const int* __restrict__ incl,
    const int* __restrict__ bsum, int* __restrict__ rowptr, int* __restrict__ cursor)
{
    int i = blockIdx.x * 256 + threadIdx.x;
    if (i >= N_NODES) return;
    int v = incl[i] + bsum[blockIdx.x];
    rowptr[i + 1] = v;
    cursor[i] = v - deg[i];
    if (i == 0) rowptr[0] = 0;
}

__global__ __launch_bounds__(256) void fill_edges_k(
    const int* __restrict__ src, const int* __restrict__ dst,
    int* __restrict__ cursor, int* __restrict__ col, int* __restrict__ dstl)
{
    int e = blockIdx.x * 256 + threadIdx.x;
    if (e >= N_EDGES) return;
    int d = dst[e];
    int pos = atomicAdd(&cursor[d], 1);
    col[pos] = src[e];
    dstl[pos] = d;
}

// ---------------- weight pre-permute into MFMA B-fragment order ----------------
template<int K>
__global__ __launch_bounds__(256) void permute_w_k(
    const float* __restrict__ w, ushort_t* __restrict__ wp)
{
    constexpr int KS = K / 32;
    int gid = blockIdx.x * 256 + threadIdx.x;
    if (gid >= K * HDIM) return;
    int idx = gid;
    int j = idx & 7; idx >>= 3;
    int lane = idx & 63; idx >>= 6;
    int ks = idx % KS;
    int ntg = idx / KS;
    int k = ks * 32 + ((lane >> 4) << 3) + j;
    int n = ntg * 16 + (lane & 15);
    wp[gid] = f2bf(w[k * HDIM + n]);
}

// ---------------- fused GIN layer: h_out = relu(relu(BN((h+Σnbr h)@W1+b1))@W2+b2) ----
// Edge-balanced gather: LDS f32 accumulator + flat edge loop with ds_add_f32.
// If POOL: segment-reduce the result into pooled instead of writing h_out.
template<int K, bool POOL>
__global__ __launch_bounds__(256) void fused_layer_k(
    const ushort_t* __restrict__ xin, const int* __restrict__ rowptr,
    const int* __restrict__ col, const int* __restrict__ dstl,
    const ushort_t* __restrict__ wp1,
    const float* __restrict__ b1, const float* __restrict__ gamma,
    const float* __restrict__ beta, const float* __restrict__ rmean,
    const float* __restrict__ rvar, const ushort_t* __restrict__ wp2,
    const float* __restrict__ b2, ushort_t* __restrict__ out,
    const int* __restrict__ batch, float* __restrict__ pooled)
{
    constexpr int KS1 = K / 32;        // K-steps of GEMM1
    constexpr int KS2 = 4;             // GEMM2 is always K=128
    constexpr int LDA = K + 8;         // bf16 stage leading dim
    constexpr int LDT = HDIM + 8;      // T leading dim = 136 (bf16)
    constexpr int LDF = K + 4;         // f32 accumulator leading dim (16B-aligned rows)
    constexpr int FPE = K / 4;         // features per edge-thread (quad per edge)
    __shared__ float    Tacc[64 * LDF];     // f32 gather accumulator
    __shared__ ushort_t A_lds[64 * LDT];    // bf16 staging (GEMM1 A, then T)
    __shared__ int batch_l[64];

    const int tid  = threadIdx.x;
    const int lane = tid & 63;
    const int wid  = tid >> 6;
    const int wm   = wid >> 1;
    const int wn   = wid & 1;
    const long long m0 = (long long)blockIdx.x * 64;

    if (POOL && tid < 64) batch_l[tid] = batch[m0 + tid];

    // ---- phase 1: self rows -> Tacc (f32) ----
    for (int i = tid; i < 64 * (K / 8); i += 256) {
        int row = i / (K / 8), c8 = i % (K / 8);
        uint4 u = *reinterpret_cast<const uint4*>(xin + (m0 + row) * (long long)K + c8 * 8);
        float4 lo = { bf2f(u.x & 0xffff), bf2f(u.x >> 16), bf2f(u.y & 0xffff), bf2f(u.y >> 16) };
        float4 hi = { bf2f(u.z & 0xffff), bf2f(u.z >> 16), bf2f(u.w & 0xffff), bf2f(u.w >> 16) };
        *reinterpret_cast<float4*>(&Tacc[row * LDF + c8 * 8])     = lo;
        *reinterpret_cast<float4*>(&Tacc[row * LDF + c8 * 8 + 4]) = hi;
    }
    __syncthreads();

    // ---- phase 2: edge-balanced neighbor accumulate (LDS f32 atomics) ----
    {
        const int p0 = rowptr[m0];
        const int p1 = rowptr[m0 + 64];
        const int nE = p1 - p0;
        const int q  = tid & 3;
        for (int e = tid >> 2; e < nE; e += 64) {
            int p    = p0 + e;
            long long srow = col[p];
            int drow = dstl[p] - (int)m0;
            int off  = ((e + q) & 3) * FPE;     // scramble quads across same-dst runs
            const uint4* sp = (const uint4*)(xin + srow * K + off);
            float* tp = &Tacc[drow * LDF + off];
            #pragma unroll
            for (int v = 0; v < FPE / 8; ++v) {
                uint4 u = sp[v];
                atomicAdd(tp + v*8 + 0, bf2f(u.x & 0xffff));
                atomicAdd(tp + v*8 + 1, bf2f(u.x >> 16));
                atomicAdd(tp + v*8 + 2, bf2f(u.y & 0xffff));
                atomicAdd(tp + v*8 + 3, bf2f(u.y >> 16));
                atomicAdd(tp + v*8 + 4, bf2f(u.z & 0xffff));
                atomicAdd(tp + v*8 + 5, bf2f(u.z >> 16));
                atomicAdd(tp + v*8 + 6, bf2f(u.w & 0xffff));
                atomicAdd(tp + v*8 + 7, bf2f(u.w >> 16));
            }
        }
    }
    __syncthreads();

    // ---- phase 3: Tacc f32 -> A_lds bf16 ----
    for (int i = tid; i < 64 * (K / 8); i += 256) {
        int row = i / (K / 8), c8 = i % (K / 8);
        const float* tp = &Tacc[row * LDF + c8 * 8];
        float4 lo = *reinterpret_cast<const float4*>(tp);
        float4 hi = *reinterpret_cast<const float4*>(tp + 4);
        uint4 u;
        u.x = (uint_t)f2bf(lo.x) | ((uint_t)f2bf(lo.y) << 16);
        u.y = (uint_t)f2bf(lo.z) | ((uint_t)f2bf(lo.w) << 16);
        u.z = (uint_t)f2bf(hi.x) | ((uint_t)f2bf(hi.y) << 16);
        u.w = (uint_t)f2bf(hi.z) | ((uint_t)f2bf(hi.w) << 16);
        *reinterpret_cast<uint4*>(&A_lds[row * LDA + c8 * 8]) = u;
    }
    __syncthreads();

    // ---- GEMM1 K-loop ----
    f32x4 acc1[2][4] = {};
    {
        short8 bfrag[4][KS1];
        #pragma unroll
        for (int nt = 0; nt < 4; ++nt)
            #pragma unroll
            for (int ks = 0; ks < KS1; ++ks) {
                int ntg = wn * 4 + nt;
                bfrag[nt][ks] = *reinterpret_cast<const short8*>(
                    wp1 + ((((ntg * KS1) + ks) * 64 + lane) << 3));
            }
        #pragma unroll
        for (int ks = 0; ks < KS1; ++ks) {
            short8 afrag[2];
            #pragma unroll
            for (int mt = 0; mt < 2; ++mt) {
                int row = wm * 32 + mt * 16 + (lane & 15);
                int c   = ks * 32 + ((lane >> 4) << 3);
                afrag[mt] = *reinterpret_cast<const short8*>(&A_lds[row * LDA + c]);
            }
            #pragma unroll
            for (int mt = 0; mt < 2; ++mt)
                #pragma unroll
                for (int nt = 0; nt < 4; ++nt)
                    acc1[mt][nt] = __builtin_amdgcn_mfma_f32_16x16x32_bf16(
                        afrag[mt], bfrag[nt][ks], acc1[mt][nt], 0, 0, 0);
        }
    }
    __syncthreads();   // all waves done reading A_lds

    // ---- BN + ReLU -> T into A_lds (LDT layout) ----
    #pragma unroll
    for (int nt = 0; nt < 4; ++nt) {
        int c = wn * 64 + nt * 16 + (lane & 15);
        float rs = rsqrtf(rvar[c] + BN_EPS);
        float scale = gamma[c] * rs;
        float shift = (b1[c] - rmean[c]) * scale + beta[c];
        #pragma unroll
        for (int mt = 0; mt < 2; ++mt) {
            int rowb = wm * 32 + mt * 16 + ((lane >> 4) << 2);
            #pragma unroll
            for (int r = 0; r < 4; ++r) {
                float v = fmaxf(acc1[mt][nt][r] * scale + shift, 0.f);
                A_lds[(rowb + r) * LDT + c] = f2bf(v);
            }
        }
    }
    __syncthreads();

    // ---- GEMM2 K-loop (K = 128 over T) ----
    f32x4 acc2[2][4] = {};
    {
        short8 bfrag[4][KS2];
        #pragma unroll
        for (int nt = 0; nt < 4; ++nt)
            #pragma unroll
            for (int ks = 0; ks < KS2; ++ks) {
                int ntg = wn * 4 + nt;
                bfrag[nt][ks] = *reinterpret_cast<const short8*>(
                    wp2 + ((((ntg * KS2) + ks) * 64 + lane) << 3));
            }
        #pragma unroll
        for (int ks = 0; ks < KS2; ++ks) {
            short8 afrag[2];
            #pragma unroll
            for (int mt = 0; mt < 2; ++mt) {
                int row = wm * 32 + mt * 16 + (lane & 15);
                int c   = ks * 32 + ((lane >> 4) << 3);
                afrag[mt] = *reinterpret_cast<const short8*>(&A_lds[row * LDT + c]);
            }
            #pragma unroll
            for (int mt = 0; mt < 2; ++mt)
                #pragma unroll
                for (int nt = 0; nt < 4; ++nt)
                    acc2[mt][nt] = __builtin_amdgcn_mfma_f32_16x16x32_bf16(
                        afrag[mt], bfrag[nt][ks], acc2[mt][nt], 0, 0, 0);
        }
    }

    if (!POOL) {
        #pragma unroll
        for (int nt = 0; nt < 4; ++nt) {
            int c = wn * 64 + nt * 16 + (lane & 15);
            float bias = b2[c];
            #pragma unroll
            for (int mt = 0; mt < 2; ++mt) {
                long long rowb = m0 + wm * 32 + mt * 16 + ((lane >> 4) << 2);
                #pragma unroll
                for (int r = 0; r < 4; ++r) {
                    float v = fmaxf(acc2[mt][nt][r] + bias, 0.f);
                    out[(rowb + r) * HDIM + c] = f2bf(v);
                }
            }
        }
    } else {
        __syncthreads();   // all waves done reading T
        #pragma unroll
        for (int nt = 0; nt < 4; ++nt) {
            int c = wn * 64 + nt * 16 + (lane & 15);
            float bias = b2[c];
            #pragma unroll
            for (int mt = 0; mt < 2; ++mt) {
                int rowb = wm * 32 + mt * 16 + ((lane >> 4) << 2);
                #pragma unroll
                for (int r = 0; r < 4; ++r) {
                    float v = fmaxf(acc2[mt][nt][r] + bias, 0.f);
                    A_lds[(rowb + r) * LDT + c] = f2bf(v);
                }
            }
        }
        __syncthreads();
        if (tid < HDIM) {
            int colw = tid;
            int curb = batch_l[0];
            float s = 0.f;
            #pragma unroll 8
            for (int r = 0; r < 64; ++r) {
                int b = batch_l[r];
                if (b != curb) {
                    atomicAdd(&pooled[(long long)curb * HDIM + colw], s);
                    curb = b; s = 0.f;
                }
                s += bf2f(A_lds[r * LDT + colw]);
            }
            atomicAdd(&pooled[(long long)curb * HDIM + colw], s);
        }
    }
}

// ---------------- head ----------------
__global__ __launch_bounds__(64) void fc_head_k(
    const float* __restrict__ pooled,
    const float* __restrict__ w_fc1, const float* __restrict__ b_fc1,
    const float* __restrict__ w_fc2, const float* __restrict__ b_fc2,
    float* __restrict__ out)
{
    int g = blockIdx.x;
    int j = threadIdx.x;   // 0..63
    __shared__ float p[HDIM];
    p[j]      = pooled[(long long)g * HDIM + j];
    p[j + 64] = pooled[(long long)g * HDIM + j + 64];
    __syncthreads();

    float acc = b_fc1[j];
    #pragma unroll 8
    for (int k = 0; k < HDIM; ++k) acc += p[k] * w_fc1[k * 64 + j];
    acc = fmaxf(acc, 0.f);

    float v = acc * w_fc2[j];
    #pragma unroll
    for (int off = 32; off > 0; off >>= 1) v += __shfl_down(v, off, 64);
    if (j == 0) out[g] = v + b_fc2[0];
}

extern "C" void kernel_launch(void* const* d_in, const int* in_sizes, int n_in,
                              void* d_out, int out_size, void* d_ws, size_t ws_size,
                              hipStream_t stream) {
    const float* x     = (const float*)d_in[0];
    const int*   ei    = (const int*)d_in[1];
    const int*   src   = ei;                // edge_index[0]
    const int*   dst   = ei + N_EDGES;      // edge_index[1]
    const int*   batch = (const int*)d_in[3];
    const float* L[3][8];
    for (int l = 0; l < 3; ++l)
        for (int p = 0; p < 8; ++p)
            L[l][p] = (const float*)d_in[4 + 8 * l + p];
    const float* w_fc1 = (const float*)d_in[30];
    const float* b_fc1 = (const float*)d_in[31];
    const float* w_fc2 = (const float*)d_in[32];
    const float* b_fc2 = (const float*)d_in[33];
    float* out = (float*)d_out;

    // ---- workspace layout (bytes) ----
    char* base = (char*)d_ws;
    ushort_t* hA     = (ushort_t*)(base);                 // bf16 [N,128] 51.2 MB
    ushort_t* hB     = (ushort_t*)(base + 51200000);      // bf16 [N,128] 51.2 MB
    ushort_t* xbf    = (ushort_t*)(base + 102400000);     // bf16 [N,32] 12.8 MB
    float*    pooled = (float*)   (base + 115200000);     // f32 [G,128] 5.12 MB
    ushort_t* wpBase = (ushort_t*)(base + 120320000);     // 172 KB
    int*      deg    = (int*)     (base + 120800000);     // 800 KB
    int*      incl   = (int*)     (base + 121600000);     // 800 KB
    int*      bsum   = (int*)     (base + 122400000);     // 4 KB
    int*      rowptr = (int*)     (base + 122404096);     // 800,004 B
    int*      cursor = (int*)     (base + 123204100);     // 800 KB
    int*      colarr = (int*)     (base + 124004100);     // 2.4 MB
    int*      dstl   = (int*)     (base + 126404100);     // 2.4 MB

    ushort_t* wp1_1 = wpBase;                 // 32*128
    ushort_t* wp2_1 = wp1_1 + 32 * HDIM;
    ushort_t* wp1_2 = wp2_1 + HDIM * HDIM;
    ushort_t* wp2_2 = wp1_2 + HDIM * HDIM;
    ushort_t* wp1_3 = wp2_2 + HDIM * HDIM;
    ushort_t* wp2_3 = wp1_3 + HDIM * HDIM;

    const int GEMM_GRID = N_NODES / 64;          // 3125 (divides exactly)
    const int NB_NODE   = (N_NODES + 255) / 256; // 782
    const int NB_EDGE   = (N_EDGES + 255) / 256; // 2344

    // ---- weight permutes + x convert ----
    permute_w_k<F_NODE><<<(F_NODE * HDIM + 255) / 256, 256, 0, stream>>>(L[0][0], wp1_1);
    permute_w_k<HDIM><<<(HDIM * HDIM + 255) / 256, 256, 0, stream>>>(L[0][6], wp2_1);
    permute_w_k<HDIM><<<(HDIM * HDIM + 255) / 256, 256, 0, stream>>>(L[1][0], wp1_2);
    permute_w_k<HDIM><<<(HDIM * HDIM + 255) / 256, 256, 0, stream>>>(L[1][6], wp2_2);
    permute_w_k<HDIM><<<(HDIM * HDIM + 255) / 256, 256, 0, stream>>>(L[2][0], wp1_3);
    permute_w_k<HDIM><<<(HDIM * HDIM + 255) / 256, 256, 0, stream>>>(L[2][6], wp2_3);
    {
        long long n8 = (long long)N_NODES * F_NODE / 8;
        cvt_bf16_k<<<(int)((n8 + 255) / 256), 256, 0, stream>>>(x, xbf, n8);
    }

    // ---- CSR build ----
    fill_zero_k<<<512, 256, 0, stream>>>((uint_t*)deg, N_NODES);
    hist_k<<<NB_EDGE, 256, 0, stream>>>(dst, deg);
    scan_blocks_k<<<NB_NODE, 256, 0, stream>>>(deg, incl, bsum);
    scan_bsum_k<<<1, 256, 0, stream>>>(bsum, NB_NODE);
    finalize_csr_k<<<NB_NODE, 256, 0, stream>>>(deg, incl, bsum, rowptr, cursor);
    fill_edges_k<<<NB_EDGE, 256, 0, stream>>>(src, dst, cursor, colarr, dstl);

    // ---- pooled zero (before layer-3 fused pool) ----
    fill_zero_k<<<512, 256, 0, stream>>>((uint_t*)pooled, (long long)N_GRAPHS * HDIM);

    // ---- 3 fused layers ----
    fused_layer_k<F_NODE, false><<<GEMM_GRID, 256, 0, stream>>>(
        xbf, rowptr, colarr, dstl, wp1_1, L[0][1], L[0][2], L[0][3], L[0][4], L[0][5],
        wp2_1, L[0][7], hA, nullptr, nullptr);
    fused_layer_k<HDIM, false><<<GEMM_GRID, 256, 0, stream>>>(
        hA, rowptr, colarr, dstl, wp1_2, L[1][1], L[1][2], L[1][3], L[1][4], L[1][5],
        wp2_2, L[1][7], hB, nullptr, nullptr);
    fused_layer_k<HDIM, true><<<GEMM_GRID, 256, 0, stream>>>(
        hB, rowptr, colarr, dstl, wp1_3, L[2][1], L[2][2], L[2][3], L[2][4], L[2][5],
        wp2_3, L[2][7], nullptr, batch, pooled);

    // ---- head ----
    fc_head_k<<<N_GRAPHS, 64, 0, stream>>>(pooled, w_fc1, b_fc1, w_fc2, b_fc2, out);
}

// Round 7
// 264.206 us; speedup vs baseline: 4.2842x; 4.2842x over previous
//
#include <hip/hip_runtime.h>

#define N_NODES 200000
#define N_EDGES 600000
#define N_GRAPHS 10000
#define F_NODE 32
#define HDIM 128
#define BN_EPS 1e-5f

typedef unsigned short ushort_t;
typedef unsigned int uint_t;
typedef __attribute__((ext_vector_type(8))) short short8;
typedef __attribute__((ext_vector_type(4))) float f32x4;

__device__ __forceinline__ ushort_t f2bf(float f) {
    uint_t u = __builtin_bit_cast(uint_t, f);
    u += 0x7FFFu + ((u >> 16) & 1u);   // RNE
    return (ushort_t)(u >> 16);
}
__device__ __forceinline__ float bf2f(ushort_t h) {
    uint_t u = ((uint_t)h) << 16;
    return __builtin_bit_cast(float, u);
}

// ---------------- zero fill ----------------
__global__ __launch_bounds__(256) void fill_zero_k(uint_t* __restrict__ p, long long n)
{
    long long gid = (long long)blockIdx.x * blockDim.x + threadIdx.x;
    long long stride = (long long)gridDim.x * blockDim.x;
    for (long long i = gid; i < n; i += stride) p[i] = 0u;
}

// ---------------- f32 -> bf16 convert (x) ----------------
__global__ __launch_bounds__(256) void cvt_bf16_k(
    const float* __restrict__ in, ushort_t* __restrict__ outp, long long n8)
{
    long long gid = (long long)blockIdx.x * blockDim.x + threadIdx.x;
    if (gid >= n8) return;
    const float4* ip = (const float4*)(in + gid * 8);
    float4 a = ip[0], b = ip[1];
    uint4 u;
    u.x = (uint_t)f2bf(a.x) | ((uint_t)f2bf(a.y) << 16);
    u.y = (uint_t)f2bf(a.z) | ((uint_t)f2bf(a.w) << 16);
    u.z = (uint_t)f2bf(b.x) | ((uint_t)f2bf(b.y) << 16);
    u.w = (uint_t)f2bf(b.z) | ((uint_t)f2bf(b.w) << 16);
    *reinterpret_cast<uint4*>(outp + gid * 8) = u;
}

// ---------------- CSR build ----------------
__global__ __launch_bounds__(256) void hist_k(const int* __restrict__ dst, int* __restrict__ deg)
{
    int e = blockIdx.x * 256 + threadIdx.x;
    if (e < N_EDGES) atomicAdd(&deg[dst[e]], 1);
}

__global__ __launch_bounds__(256) void scan_blocks_k(
    const int* __restrict__ deg, int* __restrict__ incl, int* __restrict__ bsum)
{
    __shared__ int sh[256];
    int i = blockIdx.x * 256 + threadIdx.x;
    int v = (i < N_NODES) ? deg[i] : 0;
    sh[threadIdx.x] = v;
    __syncthreads();
    #pragma unroll
    for (int off = 1; off < 256; off <<= 1) {
        int t = (threadIdx.x >= off) ? sh[threadIdx.x - off] : 0;
        __syncthreads();
        sh[threadIdx.x] += t;
        __syncthreads();
    }
    if (i < N_NODES) incl[i] = sh[threadIdx.x];
    if (threadIdx.x == 255) bsum[blockIdx.x] = sh[255];
}

__global__ __launch_bounds__(256) void scan_bsum_k(int* __restrict__ bsum, int nb)
{
    __shared__ int sh[256];
    int run = 0;
    for (int base = 0; base < nb; base += 256) {
        int i = base + threadIdx.x;
        int v = (i < nb) ? bsum[i] : 0;
        sh[threadIdx.x] = v;
        __syncthreads();
        #pragma unroll
        for (int off = 1; off < 256; off <<= 1) {
            int t = (threadIdx.x >= off) ? sh[threadIdx.x - off] : 0;
            __syncthreads();
            sh[threadIdx.x] += t;
            __syncthreads();
        }
        if (i < nb) bsum[i] = run + sh[threadIdx.x] - v;  // exclusive
        run += sh[255];
        __syncthreads();
    }
}

__global__ __launch_bounds__(256) void finalize_csr_k(
    const int* __restrict__ deg, const int* __restrict__ incl,
    const int* __restrict__ bsum, int* __restrict__ rowptr, int* __restrict__ cursor)
{
    int i = blockIdx.x * 256 + threadIdx.x;
    if (i >= N_NODES) return;
    int v = incl[i] + bsum[blockIdx.x];
    rowptr[i + 1] = v;
    cursor[i] = v - deg[i];
    if (i == 0) rowptr[0] = 0;
}

__global__ __launch_bounds__(256) void fill_edges_k(
    const int* __restrict__ src, const int* __restrict__ dst,
    int* __restrict__ cursor, int* __restrict__ col)
{
    int e = blockIdx.x * 256 + threadIdx.x;
    if (e >= N_EDGES) return;
    int pos = atomicAdd(&cursor[dst[e]], 1);
    col[pos] = src[e];
}

// ---------------- weight pre-permute into MFMA B-fragment order ----------------
template<int K>
__global__ __launch_bounds__(256) void permute_w_k(
    const float* __restrict__ w, ushort_t* __restrict__ wp)
{
    constexpr int KS = K / 32;
    int gid = blockIdx.x * 256 + threadIdx.x;
    if (gid >= K * HDIM) return;
    int idx = gid;
    int j = idx & 7; idx >>= 3;
    int lane = idx & 63; idx >>= 6;
    int ks = idx % KS;
    int ntg = idx / KS;
    int k = ks * 32 + ((lane >> 4) << 3) + j;
    int n = ntg * 16 + (lane & 15);
    wp[gid] = f2bf(w[k * HDIM + n]);
}

// ---------------- fused GIN layer: h_out = relu(relu(BN((h+Σnbr h)@W1+b1))@W2+b2) ----
// Gather: 4 threads/row, neighbor loop unrolled x2 for memory-level parallelism.
// If POOL: segment-reduce the result into pooled instead of writing h_out.
template<int K, bool POOL>
__global__ __launch_bounds__(256) void fused_layer_k(
    const ushort_t* __restrict__ xin, const int* __restrict__ rowptr,
    const int* __restrict__ col, const ushort_t* __restrict__ wp1,
    const float* __restrict__ b1, const float* __restrict__ gamma,
    const float* __restrict__ beta, const float* __restrict__ rmean,
    const float* __restrict__ rvar, const ushort_t* __restrict__ wp2,
    const float* __restrict__ b2, ushort_t* __restrict__ out,
    const int* __restrict__ batch, float* __restrict__ pooled)
{
    constexpr int KS1 = K / 32;        // K-steps of GEMM1
    constexpr int KS2 = 4;             // GEMM2 is always K=128
    constexpr int LDA = K + 8;         // bf16 stage leading dim
    constexpr int LDT = HDIM + 8;      // T leading dim = 136 (bf16)
    constexpr int FPT = K / 4;         // features per staging thread
    constexpr int NV  = FPT / 8;       // uint4 loads per row-chunk
    __shared__ ushort_t A_lds[64 * LDT];   // stage-in uses LDA <= LDT
    __shared__ int batch_l[64];

    const int tid  = threadIdx.x;
    const int lane = tid & 63;
    const int wid  = tid >> 6;
    const int wm   = wid >> 1;
    const int wn   = wid & 1;
    const long long m0 = (long long)blockIdx.x * 64;

    if (POOL && tid < 64) batch_l[tid] = batch[m0 + tid];

    // ---- gather-stage: 4 threads/row, FPT features each, f32 accumulate ----
    {
        int row = tid >> 2;
        int fq  = (tid & 3) * FPT;
        long long n = m0 + row;
        float acc[FPT];
        {
            const uint4* xp = (const uint4*)(xin + n * (long long)K + fq);
            #pragma unroll
            for (int v = 0; v < NV; ++v) {
                uint4 u = xp[v];
                acc[v*8+0]=bf2f(u.x&0xffff); acc[v*8+1]=bf2f(u.x>>16);
                acc[v*8+2]=bf2f(u.y&0xffff); acc[v*8+3]=bf2f(u.y>>16);
                acc[v*8+4]=bf2f(u.z&0xffff); acc[v*8+5]=bf2f(u.z>>16);
                acc[v*8+6]=bf2f(u.w&0xffff); acc[v*8+7]=bf2f(u.w>>16);
            }
        }
        const int p0 = rowptr[n], p1 = rowptr[n + 1];
        int p = p0;
        // 2-edge unroll: issue both col reads + all 2*NV row loads before any use
        for (; p + 2 <= p1; p += 2) {
            long long s0 = col[p];
            long long s1 = col[p + 1];
            const uint4* sp0 = (const uint4*)(xin + s0 * K + fq);
            const uint4* sp1 = (const uint4*)(xin + s1 * K + fq);
            uint4 u0[NV], u1[NV];
            #pragma unroll
            for (int v = 0; v < NV; ++v) u0[v] = sp0[v];
            #pragma unroll
            for (int v = 0; v < NV; ++v) u1[v] = sp1[v];
            #pragma unroll
            for (int v = 0; v < NV; ++v) {
                acc[v*8+0]+=bf2f(u0[v].x&0xffff)+bf2f(u1[v].x&0xffff);
                acc[v*8+1]+=bf2f(u0[v].x>>16)   +bf2f(u1[v].x>>16);
                acc[v*8+2]+=bf2f(u0[v].y&0xffff)+bf2f(u1[v].y&0xffff);
                acc[v*8+3]+=bf2f(u0[v].y>>16)   +bf2f(u1[v].y>>16);
                acc[v*8+4]+=bf2f(u0[v].z&0xffff)+bf2f(u1[v].z&0xffff);
                acc[v*8+5]+=bf2f(u0[v].z>>16)   +bf2f(u1[v].z>>16);
                acc[v*8+6]+=bf2f(u0[v].w&0xffff)+bf2f(u1[v].w&0xffff);
                acc[v*8+7]+=bf2f(u0[v].w>>16)   +bf2f(u1[v].w>>16);
            }
        }
        if (p < p1) {
            long long s = col[p];
            const uint4* sp = (const uint4*)(xin + s * K + fq);
            uint4 u[NV];
            #pragma unroll
            for (int v = 0; v < NV; ++v) u[v] = sp[v];
            #pragma unroll
            for (int v = 0; v < NV; ++v) {
                acc[v*8+0]+=bf2f(u[v].x&0xffff); acc[v*8+1]+=bf2f(u[v].x>>16);
                acc[v*8+2]+=bf2f(u[v].y&0xffff); acc[v*8+3]+=bf2f(u[v].y>>16);
                acc[v*8+4]+=bf2f(u[v].z&0xffff); acc[v*8+5]+=bf2f(u[v].z>>16);
                acc[v*8+6]+=bf2f(u[v].w&0xffff); acc[v*8+7]+=bf2f(u[v].w>>16);
            }
        }
        #pragma unroll
        for (int f = 0; f < FPT; f += 2) {
            uint_t pk = (uint_t)f2bf(acc[f]) | ((uint_t)f2bf(acc[f+1]) << 16);
            *reinterpret_cast<uint_t*>(&A_lds[row * LDA + fq + f]) = pk;
        }
    }
    __syncthreads();

    // ---- GEMM1 K-loop ----
    f32x4 acc1[2][4] = {};
    {
        short8 bfrag[4][KS1];
        #pragma unroll
        for (int nt = 0; nt < 4; ++nt)
            #pragma unroll
            for (int ks = 0; ks < KS1; ++ks) {
                int ntg = wn * 4 + nt;
                bfrag[nt][ks] = *reinterpret_cast<const short8*>(
                    wp1 + ((((ntg * KS1) + ks) * 64 + lane) << 3));
            }
        #pragma unroll
        for (int ks = 0; ks < KS1; ++ks) {
            short8 afrag[2];
            #pragma unroll
            for (int mt = 0; mt < 2; ++mt) {
                int row = wm * 32 + mt * 16 + (lane & 15);
                int c   = ks * 32 + ((lane >> 4) << 3);
                afrag[mt] = *reinterpret_cast<const short8*>(&A_lds[row * LDA + c]);
            }
            #pragma unroll
            for (int mt = 0; mt < 2; ++mt)
                #pragma unroll
                for (int nt = 0; nt < 4; ++nt)
                    acc1[mt][nt] = __builtin_amdgcn_mfma_f32_16x16x32_bf16(
                        afrag[mt], bfrag[nt][ks], acc1[mt][nt], 0, 0, 0);
        }
    }
    __syncthreads();   // all waves done reading A_lds

    // ---- BN + ReLU -> T into A_lds (LDT layout) ----
    #pragma unroll
    for (int nt = 0; nt < 4; ++nt) {
        int c = wn * 64 + nt * 16 + (lane & 15);
        float rs = rsqrtf(rvar[c] + BN_EPS);
        float scale = gamma[c] * rs;
        float shift = (b1[c] - rmean[c]) * scale + beta[c];
        #pragma unroll
        for (int mt = 0; mt < 2; ++mt) {
            int rowb = wm * 32 + mt * 16 + ((lane >> 4) << 2);
            #pragma unroll
            for (int r = 0; r < 4; ++r) {
                float v = fmaxf(acc1[mt][nt][r] * scale + shift, 0.f);
                A_lds[(rowb + r) * LDT + c] = f2bf(v);
            }
        }
    }
    __syncthreads();

    // ---- GEMM2 K-loop (K = 128 over T) ----
    f32x4 acc2[2][4] = {};
    {
        short8 bfrag[4][KS2];
        #pragma unroll
        for (int nt = 0; nt < 4; ++nt)
            #pragma unroll
            for (int ks = 0; ks < KS2; ++ks) {
                int ntg = wn * 4 + nt;
                bfrag[nt][ks] = *reinterpret_cast<const short8*>(
                    wp2 + ((((ntg * KS2) + ks) * 64 + lane) << 3));
            }
        #pragma unroll
        for (int ks = 0; ks < KS2; ++ks) {
            short8 afrag[2];
            #pragma unroll
            for (int mt = 0; mt < 2; ++mt) {
                int row = wm * 32 + mt * 16 + (lane & 15);
                int c   = ks * 32 + ((lane >> 4) << 3);
                afrag[mt] = *reinterpret_cast<const short8*>(&A_lds[row * LDT + c]);
            }
            #pragma unroll
            for (int mt = 0; mt < 2; ++mt)
                #pragma unroll
                for (int nt = 0; nt < 4; ++nt)
                    acc2[mt][nt] = __builtin_amdgcn_mfma_f32_16x16x32_bf16(
                        afrag[mt], bfrag[nt][ks], acc2[mt][nt], 0, 0, 0);
        }
    }

    if (!POOL) {
        #pragma unroll
        for (int nt = 0; nt < 4; ++nt) {
            int c = wn * 64 + nt * 16 + (lane & 15);
            float bias = b2[c];
            #pragma unroll
            for (int mt = 0; mt < 2; ++mt) {
                long long rowb = m0 + wm * 32 + mt * 16 + ((lane >> 4) << 2);
                #pragma unroll
                for (int r = 0; r < 4; ++r) {
                    float v = fmaxf(acc2[mt][nt][r] + bias, 0.f);
                    out[(rowb + r) * HDIM + c] = f2bf(v);
                }
            }
        }
    } else {
        __syncthreads();   // all waves done reading T
        #pragma unroll
        for (int nt = 0; nt < 4; ++nt) {
            int c = wn * 64 + nt * 16 + (lane & 15);
            float bias = b2[c];
            #pragma unroll
            for (int mt = 0; mt < 2; ++mt) {
                int rowb = wm * 32 + mt * 16 + ((lane >> 4) << 2);
                #pragma unroll
                for (int r = 0; r < 4; ++r) {
                    float v = fmaxf(acc2[mt][nt][r] + bias, 0.f);
                    A_lds[(rowb + r) * LDT + c] = f2bf(v);
                }
            }
        }
        __syncthreads();
        if (tid < HDIM) {
            int colw = tid;
            int curb = batch_l[0];
            float s = 0.f;
            #pragma unroll 8
            for (int r = 0; r < 64; ++r) {
                int b = batch_l[r];
                if (b != curb) {
                    atomicAdd(&pooled[(long long)curb * HDIM + colw], s);
                    curb = b; s = 0.f;
                }
                s += bf2f(A_lds[r * LDT + colw]);
            }
            atomicAdd(&pooled[(long long)curb * HDIM + colw], s);
        }
    }
}

// ---------------- head ----------------
__global__ __launch_bounds__(64) void fc_head_k(
    const float* __restrict__ pooled,
    const float* __restrict__ w_fc1, const float* __restrict__ b_fc1,
    const float* __restrict__ w_fc2, const float* __restrict__ b_fc2,
    float* __restrict__ out)
{
    int g = blockIdx.x;
    int j = threadIdx.x;   // 0..63
    __shared__ float p[HDIM];
    p[j]      = pooled[(long long)g * HDIM + j];
    p[j + 64] = pooled[(long long)g * HDIM + j + 64];
    __syncthreads();

    float acc = b_fc1[j];
    #pragma unroll 8
    for (int k = 0; k < HDIM; ++k) acc += p[k] * w_fc1[k * 64 + j];
    acc = fmaxf(acc, 0.f);

    float v = acc * w_fc2[j];
    #pragma unroll
    for (int off = 32; off > 0; off >>= 1) v += __shfl_down(v, off, 64);
    if (j == 0) out[g] = v + b_fc2[0];
}

extern "C" void kernel_launch(void* const* d_in, const int* in_sizes, int n_in,
                              void* d_out, int out_size, void* d_ws, size_t ws_size,
                              hipStream_t stream) {
    const float* x     = (const float*)d_in[0];
    const int*   ei    = (const int*)d_in[1];
    const int*   src   = ei;                // edge_index[0]
    const int*   dst   = ei + N_EDGES;      // edge_index[1]
    const int*   batch = (const int*)d_in[3];
    const float* L[3][8];
    for (int l = 0; l < 3; ++l)
        for (int p = 0; p < 8; ++p)
            L[l][p] = (const float*)d_in[4 + 8 * l + p];
    const float* w_fc1 = (const float*)d_in[30];
    const float* b_fc1 = (const float*)d_in[31];
    const float* w_fc2 = (const float*)d_in[32];
    const float* b_fc2 = (const float*)d_in[33];
    float* out = (float*)d_out;

    // ---- workspace layout (bytes) ----
    char* base = (char*)d_ws;
    ushort_t* hA     = (ushort_t*)(base);                 // bf16 [N,128] 51.2 MB
    ushort_t* hB     = (ushort_t*)(base + 51200000);      // bf16 [N,128] 51.2 MB
    ushort_t* xbf    = (ushort_t*)(base + 102400000);     // bf16 [N,32] 12.8 MB
    float*    pooled = (float*)   (base + 115200000);     // f32 [G,128] 5.12 MB
    ushort_t* wpBase = (ushort_t*)(base + 120320000);     // 172 KB
    int*      deg    = (int*)     (base + 120800000);     // 800 KB
    int*      incl   = (int*)     (base + 121600000);     // 800 KB
    int*      bsum   = (int*)     (base + 122400000);     // 4 KB
    int*      rowptr = (int*)     (base + 122404096);     // 800,004 B
    int*      cursor = (int*)     (base + 123204100);     // 800 KB
    int*      colarr = (int*)     (base + 124004100);     // 2.4 MB

    ushort_t* wp1_1 = wpBase;                 // 32*128
    ushort_t* wp2_1 = wp1_1 + 32 * HDIM;
    ushort_t* wp1_2 = wp2_1 + HDIM * HDIM;
    ushort_t* wp2_2 = wp1_2 + HDIM * HDIM;
    ushort_t* wp1_3 = wp2_2 + HDIM * HDIM;
    ushort_t* wp2_3 = wp1_3 + HDIM * HDIM;

    const int GEMM_GRID = N_NODES / 64;          // 3125 (divides exactly)
    const int NB_NODE   = (N_NODES + 255) / 256; // 782
    const int NB_EDGE   = (N_EDGES + 255) / 256; // 2344

    // ---- weight permutes + x convert ----
    permute_w_k<F_NODE><<<(F_NODE * HDIM + 255) / 256, 256, 0, stream>>>(L[0][0], wp1_1);
    permute_w_k<HDIM><<<(HDIM * HDIM + 255) / 256, 256, 0, stream>>>(L[0][6], wp2_1);
    permute_w_k<HDIM><<<(HDIM * HDIM + 255) / 256, 256, 0, stream>>>(L[1][0], wp1_2);
    permute_w_k<HDIM><<<(HDIM * HDIM + 255) / 256, 256, 0, stream>>>(L[1][6], wp2_2);
    permute_w_k<HDIM><<<(HDIM * HDIM + 255) / 256, 256, 0, stream>>>(L[2][0], wp1_3);
    permute_w_k<HDIM><<<(HDIM * HDIM + 255) / 256, 256, 0, stream>>>(L[2][6], wp2_3);
    {
        long long n8 = (long long)N_NODES * F_NODE / 8;
        cvt_bf16_k<<<(int)((n8 + 255) / 256), 256, 0, stream>>>(x, xbf, n8);
    }

    // ---- CSR build ----
    fill_zero_k<<<512, 256, 0, stream>>>((uint_t*)deg, N_NODES);
    hist_k<<<NB_EDGE, 256, 0, stream>>>(dst, deg);
    scan_blocks_k<<<NB_NODE, 256, 0, stream>>>(deg, incl, bsum);
    scan_bsum_k<<<1, 256, 0, stream>>>(bsum, NB_NODE);
    finalize_csr_k<<<NB_NODE, 256, 0, stream>>>(deg, incl, bsum, rowptr, cursor);
    fill_edges_k<<<NB_EDGE, 256, 0, stream>>>(src, dst, cursor, colarr);

    // ---- pooled zero (before layer-3 fused pool) ----
    fill_zero_k<<<512, 256, 0, stream>>>((uint_t*)pooled, (long long)N_GRAPHS * HDIM);

    // ---- 3 fused layers ----
    fused_layer_k<F_NODE, false><<<GEMM_GRID, 256, 0, stream>>>(
        xbf, rowptr, colarr, wp1_1, L[0][1], L[0][2], L[0][3], L[0][4], L[0][5],
        wp2_1, L[0][7], hA, nullptr, nullptr);
    fused_layer_k<HDIM, false><<<GEMM_GRID, 256, 0, stream>>>(
        hA, rowptr, colarr, wp1_2, L[1][1], L[1][2], L[1][3], L[1][4], L[1][5],
        wp2_2, L[1][7], hB, nullptr, nullptr);
    fused_layer_k<HDIM, true><<<GEMM_GRID, 256, 0, stream>>>(
        hB, rowptr, colarr, wp1_3, L[2][1], L[2][2], L[2][3], L[2][4], L[2][5],
        wp2_3, L[2][7], nullptr, batch, pooled);

    // ---- head ----
    fc_head_k<<<N_GRAPHS, 64, 0, stream>>>(pooled, w_fc1, b_fc1, w_fc2, b_fc2, out);
}